// Round 5
// baseline (119.077 us; speedup 1.0000x reference)
//
#include <hip/hip_runtime.h>
#include <stdint.h>

typedef short bf16x8 __attribute__((ext_vector_type(8)));
typedef float f32x4 __attribute__((ext_vector_type(4)));
typedef unsigned int u32x4 __attribute__((ext_vector_type(4)));

#define NCI 128
#define NCO 128
#define HIN 64
#define HP  66
#define NB  8

__device__ __forceinline__ unsigned short f32_to_bf16(float f) {
    union { float f; uint32_t u; } v; v.f = f;
    return (unsigned short)((v.u + 0x7FFFu + ((v.u >> 16) & 1u)) >> 16);
}

__device__ __forceinline__ void gl_lds16(const void* g, void* l) {
    __builtin_amdgcn_global_load_lds(
        (const __attribute__((address_space(1))) unsigned int*)g,
        (__attribute__((address_space(3))) unsigned int*)l, 16, 0, 0);
}

__device__ __forceinline__ void lkw0() {
    asm volatile("s_waitcnt lgkmcnt(0)" ::: "memory");
}
__device__ __forceinline__ void barx() {
    asm volatile("" ::: "memory");
    __builtin_amdgcn_s_barrier();
    asm volatile("" ::: "memory");
}

// ---- fused prologue ----
// blocks [0,1024): Weff -> Aw2[par][kt][row][pp][8], tile-major, XOR pre-swizzled.
//   content(par,kt,row,pp,e) = Weff[par][co=row][k = kt*32 + (pp ^ ((row>>1)&3))*8 + e]
// blocks [1024,1552): x [8][128][64][64] f32 -> xq [8][4][66][66][32] bf16 (chunked NHWC,
//   halo written here).
__global__ __launch_bounds__(256) void prep_kernel(
        const float* __restrict__ W, const float* __restrict__ x,
        unsigned short* __restrict__ Aw2, unsigned short* __restrict__ xq) {
    if (blockIdx.x < 1024) {
        int idx = blockIdx.x * 256 + threadIdx.x;     // 262144 total
        int e   = idx & 7;
        int pp  = (idx >> 3) & 3;
        int row = (idx >> 5) & 127;
        int kt  = (idx >> 12) & 15;
        int par = idx >> 16;
        int k   = kt * 32 + ((pp ^ ((row >> 1) & 3)) * 8) + e;
        int tap = k >> 7, ci = k & 127;
        int ty = tap >> 1, tx = tap & 1;
        int py = par >> 1, px = par & 1;
        const float* wp = W + (row * NCI + ci) * 9;
        float s = 0.f;
        #pragma unroll
        for (int ky = 0; ky < 3; ++ky) {
            bool iy = (py == 0) ? (ty == 0 ? (ky == 0) : (ky >= 1))
                                : (ty == 0 ? (ky <= 1) : (ky == 2));
            if (!iy) continue;
            #pragma unroll
            for (int kx = 0; kx < 3; ++kx) {
                bool ix = (px == 0) ? (tx == 0 ? (kx == 0) : (kx >= 1))
                                    : (tx == 0 ? (kx <= 1) : (kx == 2));
                if (ix) s += wp[ky * 3 + kx];
            }
        }
        Aw2[idx] = f32_to_bf16(s);
    } else {
        const int bb = blockIdx.x - 1024;             // 528 blocks
        const int b = bb / HP, hp = bb % HP;
        const int t = threadIdx.x;
        if (hp == 0 || hp == HP - 1) {                // top/bottom halo rows, all 4 chunks
            bf16x8 z = (bf16x8){0, 0, 0, 0, 0, 0, 0, 0};
            for (int i = t; i < 4 * HP * 4; i += 256) {
                int g = i / (HP * 4), rem = i % (HP * 4);
                unsigned short* dst = xq +
                    ((((size_t)(b * 4 + g) * HP + hp) * HP) << 5) + rem * 8;
                *(bf16x8*)dst = z;
            }
            return;
        }
        const int h = hp - 1;
        if (t < 32) {                                  // column halo wp = 0, 65
            bf16x8 z = (bf16x8){0, 0, 0, 0, 0, 0, 0, 0};
            int g = t >> 3, wpc = ((t >> 2) & 1) * (HP - 1), q = t & 3;
            unsigned short* dst = xq +
                ((((size_t)(b * 4 + g) * HP + hp) * HP + wpc) << 5) + q * 8;
            *(bf16x8*)dst = z;
        }
        const int w = t & 63, g = t >> 6;
        const float* src = x + ((size_t)(b * NCI + g * 32) * (HIN * HIN)) + h * HIN + w;
        unsigned short* dst = xq +
            ((((size_t)(b * 4 + g) * HP + hp) * HP + (w + 1)) << 5);
        #pragma unroll
        for (int q = 0; q < 4; ++q) {
            bf16x8 v;
            #pragma unroll
            for (int j = 0; j < 8; ++j)
                v[j] = (short)f32_to_bf16(src[(size_t)(q * 8 + j) * (HIN * HIN)]);
            *(bf16x8*)(dst + q * 8) = v;
        }
    }
}

// Main GEMM: counted-vmcnt pipeline (T3/T4). A direct global->reg (ping-pong,
// 1-ahead); B via gl_lds into 3-buffer LDS (2-ahead). One wait + one raw
// barrier per K-step; vmcnt never 0 in steady state.
__global__ __launch_bounds__(512, 4) void upconv5_kernel(
        const unsigned short* __restrict__ xq, const unsigned short* __restrict__ Aw2,
        const float* __restrict__ bv, float* __restrict__ out) {
    __shared__ __align__(16) unsigned short smem[3 * 2 * 4096];   // 48 KB (B only)
    // bijective XCD chunk swizzle (512 % 8 == 0)
    const int d = blockIdx.x;
    const int dsw = (d & 7) * 64 + (d >> 3);
    const int tile = dsw >> 1, py = dsw & 1;
    const int bi = tile >> 5;
    const int oy0 = (tile & 31) * 2;
    const int tid = threadIdx.x, lane = tid & 63, wv = tid >> 6;
    const int pxw = wv >> 2, wm = (wv >> 1) & 1, wn = wv & 1;
    const int rl = lane & 15, pl = lane >> 4;

    // B staging map: physical LDS slot tid*8 <-> (row=tid>>2, pp=tid&3);
    // source supplies logical part pp ^ ((row>>1)&3)
    const int srow = tid >> 2;
    const int pL = (tid & 3) ^ ((srow >> 1) & 3);
    const int box = srow & 63;
    const int boy = oy0 + (srow >> 6);

    const unsigned short* Abase = Aw2 + (((py * 2 + pxw) * 16) << 12);

    f32x4 acc[4][4];
    #pragma unroll
    for (int i = 0; i < 4; ++i)
        #pragma unroll
        for (int j = 0; j < 4; ++j)
            acc[i][j] = (f32x4){0.f, 0.f, 0.f, 0.f};

    auto stageB = [&](int st, int kt) {
        const int g = kt & 3, tx = (kt >> 2) & 1, ty = kt >> 3;
        const int rowg = boy + py + ty;
        #pragma unroll
        for (int px = 0; px < 2; ++px) {
            const unsigned short* gb = xq +
                ((((size_t)(bi * 4 + g) * HP + rowg) * HP + (box + px + tx)) << 5) + pL * 8;
            gl_lds16(gb, &smem[(st * 2 + px) * 4096 + tid * 8]);
        }
    };
    auto loadA = [&](bf16x8* Adst, int kt) {
        #pragma unroll
        for (int f = 0; f < 4; ++f) {
            int ar = wm * 64 + f * 16 + rl;
            Adst[f] = *(const bf16x8*)(Abase + (kt << 12) + ar * 32 +
                                       ((pl ^ ((ar >> 1) & 3)) * 8));
        }
    };

    bf16x8 A0[4], A1[4];
    stageB(0, 0);                 // vm: B0(2)
    stageB(1, 1);                 // vm: B0(2) B1(2)
    loadA(A0, 0);                 // vm: B0(2) B1(2) A0(4)
    asm volatile("s_waitcnt vmcnt(6)" ::: "memory");   // retire B0
    barx();

    #pragma unroll
    for (int t = 0; t < 16; ++t) {
        if (t + 2 < 16) stageB((t + 2) % 3, t + 2);
        if (t + 1 < 16) loadA((t & 1) ? A0 : A1, t + 1);
        // steady outstanding: [B(t+1)2, A(t)4, B(t+2)2, A(t+1)4] -> retire A(t)
        if (t <= 13)      { asm volatile("s_waitcnt vmcnt(6)" ::: "memory"); }
        else if (t == 14) { asm volatile("s_waitcnt vmcnt(4)" ::: "memory"); }
        else              { asm volatile("s_waitcnt vmcnt(0)" ::: "memory"); }

        const unsigned short* sb = &smem[(((t % 3) * 2 + pxw) * 4096)];
        bf16x8 bfr[4];
        #pragma unroll
        for (int f = 0; f < 4; ++f) {
            int bn = wn * 64 + f * 16 + rl;
            bfr[f] = *(const bf16x8*)&sb[bn * 32 + ((pl ^ ((bn >> 1) & 3)) * 8)];
        }
        const bf16x8* Ac = (t & 1) ? A1 : A0;
        #pragma unroll
        for (int fm = 0; fm < 4; ++fm)
            #pragma unroll
            for (int fn = 0; fn < 4; ++fn)
                acc[fm][fn] = __builtin_amdgcn_mfma_f32_16x16x32_bf16(
                    Ac[fm], bfr[fn], acc[fm][fn], 0, 0, 0);
        barx();
    }

    // coalesced epilogue via LDS: lf[co_l 0..31][r 0..1][xx 0..127], stride 264
    float* lf = (float*)smem;
    const int co_l = tid >> 4;
    const int rem = tid & 15, rr = rem >> 3, x16 = (rem & 7) * 16;
    const int co_g = (co_l >> 4) * 64 + (co_l & 15);
    const int yy = 2 * (oy0 + rr) + py;

    #pragma unroll
    for (int fm = 0; fm < 4; ++fm) {
        #pragma unroll
        for (int fn = 0; fn < 4; ++fn) {
            int n = wn * 64 + fn * 16 + rl;
            int r = n >> 6, xx = 2 * (n & 63) + pxw;
            #pragma unroll
            for (int j = 0; j < 4; ++j) {
                int col = wm * 16 + pl * 4 + j;
                lf[col * 264 + r * 132 + xx] = acc[fm][fn][j];
            }
        }
        lkw0();
        barx();
        const int co = co_g + fm * 16;
        const float bb = bv[co];
        float* op = out + (((size_t)bi * NCO + co) * 128 + yy) * 128 + x16;
        const float* sp = lf + co_l * 264 + rr * 132 + x16;
        #pragma unroll
        for (int q = 0; q < 4; ++q) {
            f32x4 v = *(const f32x4*)(sp + q * 4);
            v[0] += bb; v[1] += bb; v[2] += bb; v[3] += bb;
            *(f32x4*)(op + q * 4) = v;
        }
        if (fm < 3) barx();
    }
}

// -------- fallback (ws too small for xq): reads x f32 directly, Aw2 layout --------
__global__ __launch_bounds__(256) void upconv_fb_kernel(
        const float* __restrict__ x, const unsigned short* __restrict__ Aw2,
        const float* __restrict__ bv, float* __restrict__ out) {
    __shared__ __align__(16) unsigned short A_lds[128 * 32];
    __shared__ __align__(16) unsigned short B_lds[128 * 32];
    const int par = blockIdx.y, py = par >> 1, px = par & 1;
    const int s0 = blockIdx.x * 128;
    const int bimg = s0 >> 12;
    const int oy0 = (s0 >> 6) & 63;
    const int tid = threadIdx.x;
    const int lane = tid & 63, wave = tid >> 6;
    const int wm = wave >> 1, wn = wave & 1;
    const float* xb = x + bimg * (NCI * HIN * HIN);
    f32x4 acc[4][4];
    #pragma unroll
    for (int i = 0; i < 4; ++i)
        #pragma unroll
        for (int j = 0; j < 4; ++j)
            acc[i][j] = (f32x4){0.f, 0.f, 0.f, 0.f};
    for (int kt = 0; kt < 16; ++kt) {
        const int tap = kt >> 2, ci0 = (kt & 3) * 32;
        const int ty = tap >> 1, tx = tap & 1;
        #pragma unroll
        for (int i = 0; i < 2; ++i) {
            int c = i * 256 + tid;
            *(bf16x8*)(&A_lds[c * 8]) =
                *(const bf16x8*)(Aw2 + ((par * 16 + kt) << 12) + c * 8);
        }
        #pragma unroll
        for (int i = 0; i < 2; ++i) {
            int tsk = i * 256 + tid;
            int n = tsk & 127, kg = tsk >> 7;
            int r = n >> 6, ox = n & 63;
            int row = oy0 + r - 1 + py + ty;
            int col = ox - 1 + px + tx;
            bool ok = (row >= 0) & (row < HIN) & (col >= 0) & (col < HIN);
            const float* xp = xb + (((ci0 + kg * 8) * HIN + row) * HIN + col);
            bf16x8 v;
            #pragma unroll
            for (int q = 0; q < 8; ++q) {
                float f = ok ? xp[q * (HIN * HIN)] : 0.f;
                v[q] = (short)f32_to_bf16(f);
            }
            *(bf16x8*)(&B_lds[n * 32 + kg * 8]) = v;
        }
        __syncthreads();
        const int rl2 = lane & 15, pl2 = lane >> 4;
        bf16x8 af[4], bfr[4];
        #pragma unroll
        for (int f = 0; f < 4; ++f) {
            int ar = wm * 64 + f * 16 + rl2;
            af[f] = *(const bf16x8*)(&A_lds[ar * 32 + ((pl2 ^ ((ar >> 1) & 3)) * 8)]);
            bfr[f] = *(const bf16x8*)(&B_lds[(wn * 64 + f * 16 + rl2) * 32 + pl2 * 8]);
        }
        #pragma unroll
        for (int fm = 0; fm < 4; ++fm)
            #pragma unroll
            for (int fn = 0; fn < 4; ++fn)
                acc[fm][fn] = __builtin_amdgcn_mfma_f32_16x16x32_bf16(
                    af[fm], bfr[fn], acc[fm][fn], 0, 0, 0);
        __syncthreads();
    }
    #pragma unroll
    for (int fm = 0; fm < 4; ++fm) {
        const int co_b = wm * 64 + fm * 16 + (lane >> 4) * 4;
        float bias4[4];
        #pragma unroll
        for (int j = 0; j < 4; ++j) bias4[j] = bv[co_b + j];
        #pragma unroll
        for (int fn = 0; fn < 4; ++fn) {
            int n = wn * 64 + fn * 16 + (lane & 15);
            int s = s0 + n;
            int ox = s & 63, oy = (s >> 6) & 63, bi2 = s >> 12;
            int yy = 2 * oy + py, xx = 2 * ox + px;
            float* op = out + ((size_t)bi2 * 128 * 128 * 128) + (size_t)yy * 128 + xx;
            #pragma unroll
            for (int j = 0; j < 4; ++j)
                op[(size_t)(co_b + j) * (128 * 128)] = acc[fm][fn][j] + bias4[j];
        }
    }
}

extern "C" void kernel_launch(void* const* d_in, const int* in_sizes, int n_in,
                              void* d_out, int out_size, void* d_ws, size_t ws_size,
                              hipStream_t stream) {
    const float* x  = (const float*)d_in[0];
    const float* W  = (const float*)d_in[1];
    const float* bv = (const float*)d_in[2];
    float* out = (float*)d_out;
    unsigned short* Aw2 = (unsigned short*)d_ws;              // 512 KB
    const size_t aw_bytes = 4 * 16 * 128 * 32 * sizeof(unsigned short);
    const size_t xq_bytes = (size_t)NB * 4 * HP * HP * 32 * sizeof(unsigned short);

    if (ws_size >= aw_bytes + xq_bytes) {
        unsigned short* xq = (unsigned short*)((char*)d_ws + aw_bytes);
        prep_kernel<<<1024 + NB * HP, 256, 0, stream>>>(W, x, Aw2, xq);
        upconv5_kernel<<<512, 512, 0, stream>>>(xq, Aw2, bv, out);
    } else {
        prep_kernel<<<1024, 256, 0, stream>>>(W, x, Aw2, (unsigned short*)nullptr);
        upconv_fb_kernel<<<dim3(256, 4), 256, 0, stream>>>(x, Aw2, bv, out);
    }
}

// Round 6
// 55.517 us; speedup vs baseline: 2.1449x; 2.1449x over previous
//
#include <hip/hip_runtime.h>
#include <stdint.h>

typedef short bf16x8 __attribute__((ext_vector_type(8)));
typedef float f32x4 __attribute__((ext_vector_type(4)));
typedef unsigned int u32x4 __attribute__((ext_vector_type(4)));

#define NCI 128
#define NCO 128
#define HIN 64
#define HP  66
#define NB  8

__device__ __forceinline__ unsigned short f32_to_bf16(float f) {
    union { float f; uint32_t u; } v; v.f = f;
    return (unsigned short)((v.u + 0x7FFFu + ((v.u >> 16) & 1u)) >> 16);
}

__device__ __forceinline__ void gl_lds16(const void* g, void* l) {
    __builtin_amdgcn_global_load_lds(
        (const __attribute__((address_space(1))) unsigned int*)g,
        (__attribute__((address_space(3))) unsigned int*)l, 16, 0, 0);
}

__device__ __forceinline__ void lkw0() {
    asm volatile("s_waitcnt lgkmcnt(0)" ::: "memory");
}
__device__ __forceinline__ void barx() {
    asm volatile("" ::: "memory");
    __builtin_amdgcn_s_barrier();
    asm volatile("" ::: "memory");
}

// ---- fused prologue ----
// blocks [0,1024): Weff -> Aw2[par][kt][row][pp][8], tile-major, XOR pre-swizzled.
// blocks [1024,1552): x [8][128][64][64] f32 -> xq [8][4][66][66][32] bf16 (chunked
//   NHWC, halo written here).
__global__ __launch_bounds__(256) void prep_kernel(
        const float* __restrict__ W, const float* __restrict__ x,
        unsigned short* __restrict__ Aw2, unsigned short* __restrict__ xq) {
    if (blockIdx.x < 1024) {
        int idx = blockIdx.x * 256 + threadIdx.x;     // 262144 total
        int e   = idx & 7;
        int pp  = (idx >> 3) & 3;
        int row = (idx >> 5) & 127;
        int kt  = (idx >> 12) & 15;
        int par = idx >> 16;
        int k   = kt * 32 + ((pp ^ ((row >> 1) & 3)) * 8) + e;
        int tap = k >> 7, ci = k & 127;
        int ty = tap >> 1, tx = tap & 1;
        int py = par >> 1, px = par & 1;
        const float* wp = W + (row * NCI + ci) * 9;
        float s = 0.f;
        #pragma unroll
        for (int ky = 0; ky < 3; ++ky) {
            bool iy = (py == 0) ? (ty == 0 ? (ky == 0) : (ky >= 1))
                                : (ty == 0 ? (ky <= 1) : (ky == 2));
            if (!iy) continue;
            #pragma unroll
            for (int kx = 0; kx < 3; ++kx) {
                bool ix = (px == 0) ? (tx == 0 ? (kx == 0) : (kx >= 1))
                                    : (tx == 0 ? (kx <= 1) : (kx == 2));
                if (ix) s += wp[ky * 3 + kx];
            }
        }
        Aw2[idx] = f32_to_bf16(s);
    } else {
        const int bb = blockIdx.x - 1024;             // 528 blocks
        const int b = bb / HP, hp = bb % HP;
        const int t = threadIdx.x;
        if (hp == 0 || hp == HP - 1) {
            bf16x8 z = (bf16x8){0, 0, 0, 0, 0, 0, 0, 0};
            for (int i = t; i < 4 * HP * 4; i += 256) {
                int g = i / (HP * 4), rem = i % (HP * 4);
                unsigned short* dst = xq +
                    ((((size_t)(b * 4 + g) * HP + hp) * HP) << 5) + rem * 8;
                *(bf16x8*)dst = z;
            }
            return;
        }
        const int h = hp - 1;
        if (t < 32) {                                  // column halo wp = 0, 65
            bf16x8 z = (bf16x8){0, 0, 0, 0, 0, 0, 0, 0};
            int g = t >> 3, wpc = ((t >> 2) & 1) * (HP - 1), q = t & 3;
            unsigned short* dst = xq +
                ((((size_t)(b * 4 + g) * HP + hp) * HP + wpc) << 5) + q * 8;
            *(bf16x8*)dst = z;
        }
        const int w = t & 63, g = t >> 6;
        const float* src = x + ((size_t)(b * NCI + g * 32) * (HIN * HIN)) + h * HIN + w;
        unsigned short* dst = xq +
            ((((size_t)(b * 4 + g) * HP + hp) * HP + (w + 1)) << 5);
        #pragma unroll
        for (int q = 0; q < 4; ++q) {
            bf16x8 v;
            #pragma unroll
            for (int j = 0; j < 8; ++j)
                v[j] = (short)f32_to_bf16(src[(size_t)(q * 8 + j) * (HIN * HIN)]);
            *(bf16x8*)(dst + q * 8) = v;
        }
    }
}

// Main GEMM: counted-vmcnt pipeline (T3/T4). A direct global->reg (ping-pong,
// 1-ahead); B via gl_lds into 3-buffer LDS (2-ahead). One wait + one raw
// barrier per K-step. launch_bounds(512,2): 256-reg cap, no spills.
__global__ __launch_bounds__(512, 2) void upconv6_kernel(
        const unsigned short* __restrict__ xq, const unsigned short* __restrict__ Aw2,
        const float* __restrict__ bv, float* __restrict__ out) {
    __shared__ __align__(16) unsigned short smem[3 * 2 * 4096];   // 48 KB (B only)
    const int d = blockIdx.x;
    const int dsw = (d & 7) * 64 + (d >> 3);     // bijective XCD chunk swizzle
    const int tile = dsw >> 1, py = dsw & 1;
    const int bi = tile >> 5;
    const int oy0 = (tile & 31) * 2;
    const int tid = threadIdx.x, lane = tid & 63, wv = tid >> 6;
    const int pxw = wv >> 2, wm = (wv >> 1) & 1, wn = wv & 1;
    const int rl = lane & 15, pl = lane >> 4;

    const int srow = tid >> 2;
    const int pL = (tid & 3) ^ ((srow >> 1) & 3);
    const int box = srow & 63;
    const int boy = oy0 + (srow >> 6);

    const unsigned short* Abase = Aw2 + (((py * 2 + pxw) * 16) << 12);

    f32x4 acc[4][4];
    #pragma unroll
    for (int i = 0; i < 4; ++i)
        #pragma unroll
        for (int j = 0; j < 4; ++j)
            acc[i][j] = (f32x4){0.f, 0.f, 0.f, 0.f};

    auto stageB = [&](int st, int kt) {
        const int g = kt & 3, tx = (kt >> 2) & 1, ty = kt >> 3;
        const int rowg = boy + py + ty;
        #pragma unroll
        for (int px = 0; px < 2; ++px) {
            const unsigned short* gb = xq +
                ((((size_t)(bi * 4 + g) * HP + rowg) * HP + (box + px + tx)) << 5) + pL * 8;
            gl_lds16(gb, &smem[(st * 2 + px) * 4096 + tid * 8]);
        }
    };
    auto loadA = [&](bf16x8* Adst, int kt) {
        #pragma unroll
        for (int f = 0; f < 4; ++f) {
            int ar = wm * 64 + f * 16 + rl;
            Adst[f] = *(const bf16x8*)(Abase + (kt << 12) + ar * 32 +
                                       ((pl ^ ((ar >> 1) & 3)) * 8));
        }
    };

    bf16x8 A0[4], A1[4];
    stageB(0, 0);                 // vm: B0(2)
    stageB(1, 1);                 // vm: B0 B1
    loadA(A0, 0);                 // vm: B0 B1 A0 -> 8
    asm volatile("s_waitcnt vmcnt(6)" ::: "memory");   // retire B0
    barx();

    #pragma unroll 2
    for (int t = 0; t < 16; ++t) {
        if (t + 2 < 16) stageB((t + 2) % 3, t + 2);
        if (t + 1 < 16) loadA((t & 1) ? A0 : A1, t + 1);
        // steady outstanding before wait: B(t+1)2 A(t)4 B(t+2)2 A(t+1)4 = 12
        // -> retire oldest 6 = B(t+1), A(t)
        if (t <= 13)      { asm volatile("s_waitcnt vmcnt(6)" ::: "memory"); }
        else if (t == 14) { asm volatile("s_waitcnt vmcnt(4)" ::: "memory"); }
        else              { asm volatile("s_waitcnt vmcnt(0)" ::: "memory"); }

        const unsigned short* sb = &smem[(((t % 3) * 2 + pxw) * 4096)];
        bf16x8 bfr[4];
        #pragma unroll
        for (int f = 0; f < 4; ++f) {
            int bn = wn * 64 + f * 16 + rl;
            bfr[f] = *(const bf16x8*)&sb[bn * 32 + ((pl ^ ((bn >> 1) & 3)) * 8)];
        }
        const bf16x8* Ac = (t & 1) ? A1 : A0;
        #pragma unroll
        for (int fm = 0; fm < 4; ++fm)
            #pragma unroll
            for (int fn = 0; fn < 4; ++fn)
                acc[fm][fn] = __builtin_amdgcn_mfma_f32_16x16x32_bf16(
                    Ac[fm], bfr[fn], acc[fm][fn], 0, 0, 0);
        barx();
    }

    // coalesced epilogue via LDS: lf[co_l 0..31][r 0..1][xx 0..127], stride 264
    float* lf = (float*)smem;
    const int co_l = tid >> 4;
    const int rem = tid & 15, rr = rem >> 3, x16 = (rem & 7) * 16;
    const int co_g = (co_l >> 4) * 64 + (co_l & 15);
    const int yy = 2 * (oy0 + rr) + py;

    #pragma unroll
    for (int fm = 0; fm < 4; ++fm) {
        #pragma unroll
        for (int fn = 0; fn < 4; ++fn) {
            int n = wn * 64 + fn * 16 + rl;
            int r = n >> 6, xx = 2 * (n & 63) + pxw;
            #pragma unroll
            for (int j = 0; j < 4; ++j) {
                int col = wm * 16 + pl * 4 + j;
                lf[col * 264 + r * 132 + xx] = acc[fm][fn][j];
            }
        }
        lkw0();
        barx();
        const int co = co_g + fm * 16;
        const float bb = bv[co];
        float* op = out + (((size_t)bi * NCO + co) * 128 + yy) * 128 + x16;
        const float* sp = lf + co_l * 264 + rr * 132 + x16;
        #pragma unroll
        for (int q = 0; q < 4; ++q) {
            f32x4 v = *(const f32x4*)(sp + q * 4);
            v[0] += bb; v[1] += bb; v[2] += bb; v[3] += bb;
            *(f32x4*)(op + q * 4) = v;
        }
        if (fm < 3) barx();
    }
}

// -------- fallback (ws too small for xq): reads x f32 directly, Aw2 layout --------
__global__ __launch_bounds__(256) void upconv_fb_kernel(
        const float* __restrict__ x, const unsigned short* __restrict__ Aw2,
        const float* __restrict__ bv, float* __restrict__ out) {
    __shared__ __align__(16) unsigned short A_lds[128 * 32];
    __shared__ __align__(16) unsigned short B_lds[128 * 32];
    const int par = blockIdx.y, py = par >> 1, px = par & 1;
    const int s0 = blockIdx.x * 128;
    const int bimg = s0 >> 12;
    const int oy0 = (s0 >> 6) & 63;
    const int tid = threadIdx.x;
    const int lane = tid & 63, wave = tid >> 6;
    const int wm = wave >> 1, wn = wave & 1;
    const float* xb = x + bimg * (NCI * HIN * HIN);
    f32x4 acc[4][4];
    #pragma unroll
    for (int i = 0; i < 4; ++i)
        #pragma unroll
        for (int j = 0; j < 4; ++j)
            acc[i][j] = (f32x4){0.f, 0.f, 0.f, 0.f};
    for (int kt = 0; kt < 16; ++kt) {
        const int tap = kt >> 2, ci0 = (kt & 3) * 32;
        const int ty = tap >> 1, tx = tap & 1;
        #pragma unroll
        for (int i = 0; i < 2; ++i) {
            int c = i * 256 + tid;
            *(bf16x8*)(&A_lds[c * 8]) =
                *(const bf16x8*)(Aw2 + ((par * 16 + kt) << 12) + c * 8);
        }
        #pragma unroll
        for (int i = 0; i < 2; ++i) {
            int tsk = i * 256 + tid;
            int n = tsk & 127, kg = tsk >> 7;
            int r = n >> 6, ox = n & 63;
            int row = oy0 + r - 1 + py + ty;
            int col = ox - 1 + px + tx;
            bool ok = (row >= 0) & (row < HIN) & (col >= 0) & (col < HIN);
            const float* xp = xb + (((ci0 + kg * 8) * HIN + row) * HIN + col);
            bf16x8 v;
            #pragma unroll
            for (int q = 0; q < 8; ++q) {
                float f = ok ? xp[q * (HIN * HIN)] : 0.f;
                v[q] = (short)f32_to_bf16(f);
            }
            *(bf16x8*)(&B_lds[n * 32 + kg * 8]) = v;
        }
        __syncthreads();
        const int rl2 = lane & 15, pl2 = lane >> 4;
        bf16x8 af[4], bfr[4];
        #pragma unroll
        for (int f = 0; f < 4; ++f) {
            int ar = wm * 64 + f * 16 + rl2;
            af[f] = *(const bf16x8*)(&A_lds[ar * 32 + ((pl2 ^ ((ar >> 1) & 3)) * 8)]);
            bfr[f] = *(const bf16x8*)(&B_lds[(wn * 64 + f * 16 + rl2) * 32 + pl2 * 8]);
        }
        #pragma unroll
        for (int fm = 0; fm < 4; ++fm)
            #pragma unroll
            for (int fn = 0; fn < 4; ++fn)
                acc[fm][fn] = __builtin_amdgcn_mfma_f32_16x16x32_bf16(
                    af[fm], bfr[fn], acc[fm][fn], 0, 0, 0);
        __syncthreads();
    }
    #pragma unroll
    for (int fm = 0; fm < 4; ++fm) {
        const int co_b = wm * 64 + fm * 16 + (lane >> 4) * 4;
        float bias4[4];
        #pragma unroll
        for (int j = 0; j < 4; ++j) bias4[j] = bv[co_b + j];
        #pragma unroll
        for (int fn = 0; fn < 4; ++fn) {
            int n = wn * 64 + fn * 16 + (lane & 15);
            int s = s0 + n;
            int ox = s & 63, oy = (s >> 6) & 63, bi2 = s >> 12;
            int yy = 2 * oy + py, xx = 2 * ox + px;
            float* op = out + ((size_t)bi2 * 128 * 128 * 128) + (size_t)yy * 128 + xx;
            #pragma unroll
            for (int j = 0; j < 4; ++j)
                op[(size_t)(co_b + j) * (128 * 128)] = acc[fm][fn][j] + bias4[j];
        }
    }
}

extern "C" void kernel_launch(void* const* d_in, const int* in_sizes, int n_in,
                              void* d_out, int out_size, void* d_ws, size_t ws_size,
                              hipStream_t stream) {
    const float* x  = (const float*)d_in[0];
    const float* W  = (const float*)d_in[1];
    const float* bv = (const float*)d_in[2];
    float* out = (float*)d_out;
    unsigned short* Aw2 = (unsigned short*)d_ws;              // 512 KB
    const size_t aw_bytes = 4 * 16 * 128 * 32 * sizeof(unsigned short);
    const size_t xq_bytes = (size_t)NB * 4 * HP * HP * 32 * sizeof(unsigned short);

    if (ws_size >= aw_bytes + xq_bytes) {
        unsigned short* xq = (unsigned short*)((char*)d_ws + aw_bytes);
        prep_kernel<<<1024 + NB * HP, 256, 0, stream>>>(W, x, Aw2, xq);
        upconv6_kernel<<<512, 512, 0, stream>>>(xq, Aw2, bv, out);
    } else {
        prep_kernel<<<1024, 256, 0, stream>>>(W, x, Aw2, (unsigned short*)nullptr);
        upconv_fb_kernel<<<dim3(256, 4), 256, 0, stream>>>(x, Aw2, bv, out);
    }
}

// Round 7
// 54.938 us; speedup vs baseline: 2.1675x; 1.0105x over previous
//
#include <hip/hip_runtime.h>
#include <stdint.h>

typedef short bf16x8 __attribute__((ext_vector_type(8)));
typedef float f32x4 __attribute__((ext_vector_type(4)));

#define NCI 128
#define NCO 128
#define HIN 64
#define HP  66
#define NB  8

__device__ __forceinline__ unsigned short f32_to_bf16(float f) {
    union { float f; uint32_t u; } v; v.f = f;
    return (unsigned short)((v.u + 0x7FFFu + ((v.u >> 16) & 1u)) >> 16);
}

__device__ __forceinline__ void gl_lds16(const void* g, void* l) {
    __builtin_amdgcn_global_load_lds(
        (const __attribute__((address_space(1))) unsigned int*)g,
        (__attribute__((address_space(3))) unsigned int*)l, 16, 0, 0);
}

__device__ __forceinline__ void vmw0() {
    asm volatile("s_waitcnt vmcnt(0)" ::: "memory");
}
__device__ __forceinline__ void lkw0() {
    asm volatile("s_waitcnt lgkmcnt(0)" ::: "memory");
}
__device__ __forceinline__ void barx() {
    asm volatile("" ::: "memory");
    __builtin_amdgcn_s_barrier();
    asm volatile("" ::: "memory");
}

// Weff math shared by prep/fallback: effective 2x2-tap weight for parity (py,px)
__device__ __forceinline__ float weff_sum(const float* wp, int py, int px, int ty, int tx) {
    float s = 0.f;
    #pragma unroll
    for (int ky = 0; ky < 3; ++ky) {
        bool iy = (py == 0) ? (ty == 0 ? (ky == 0) : (ky >= 1))
                            : (ty == 0 ? (ky <= 1) : (ky == 2));
        if (!iy) continue;
        #pragma unroll
        for (int kx = 0; kx < 3; ++kx) {
            bool ix = (px == 0) ? (tx == 0 ? (kx == 0) : (kx >= 1))
                                : (tx == 0 ? (kx <= 1) : (kx == 2));
            if (ix) s += wp[ky * 3 + kx];
        }
    }
    return s;
}

// ---- fused prologue ----
// blocks [0,1024): Weff -> Aw3[par][u][s][e]: BK=64 tile-major, XOR pre-swizzled.
//   s in [0,1024): row = s>>3, partP = s&7, partL = partP ^ (row&7),
//   content = Weff[par][co=row][k = u*64 + partL*8 + e]
// blocks [1024,1552): x [8][128][64][64] f32 -> xq [8][4][66][66][32] bf16
//   (ci-chunked NHWC, halo written here).
__global__ __launch_bounds__(256) void prep_kernel(
        const float* __restrict__ W, const float* __restrict__ x,
        unsigned short* __restrict__ Aw3, unsigned short* __restrict__ xq) {
    if (blockIdx.x < 1024) {
        int idx = blockIdx.x * 256 + threadIdx.x;     // 262144 total
        int e   = idx & 7;
        int s   = (idx >> 3) & 1023;
        int u   = (idx >> 13) & 7;
        int par = idx >> 16;
        int row = s >> 3, partP = s & 7;
        int partL = partP ^ (row & 7);
        int k = u * 64 + partL * 8 + e;
        int tap = k >> 7, ci = k & 127;
        int ty = tap >> 1, tx = tap & 1;
        int py = par >> 1, px = par & 1;
        Aw3[idx] = f32_to_bf16(weff_sum(W + (row * NCI + ci) * 9, py, px, ty, tx));
    } else {
        const int bb = blockIdx.x - 1024;             // 528 blocks
        const int b = bb / HP, hp = bb % HP;
        const int t = threadIdx.x;
        if (hp == 0 || hp == HP - 1) {
            bf16x8 z = (bf16x8){0, 0, 0, 0, 0, 0, 0, 0};
            for (int i = t; i < 4 * HP * 4; i += 256) {
                int g = i / (HP * 4), rem = i % (HP * 4);
                unsigned short* dst = xq +
                    ((((size_t)(b * 4 + g) * HP + hp) * HP) << 5) + rem * 8;
                *(bf16x8*)dst = z;
            }
            return;
        }
        const int h = hp - 1;
        if (t < 32) {                                  // column halo wp = 0, 65
            bf16x8 z = (bf16x8){0, 0, 0, 0, 0, 0, 0, 0};
            int g = t >> 3, wpc = ((t >> 2) & 1) * (HP - 1), q = t & 3;
            unsigned short* dst = xq +
                ((((size_t)(b * 4 + g) * HP + hp) * HP + wpc) << 5) + q * 8;
            *(bf16x8*)dst = z;
        }
        const int w = t & 63, g = t >> 6;
        const float* src = x + ((size_t)(b * NCI + g * 32) * (HIN * HIN)) + h * HIN + w;
        unsigned short* dst = xq +
            ((((size_t)(b * 4 + g) * HP + hp) * HP + (w + 1)) << 5);
        #pragma unroll
        for (int q = 0; q < 4; ++q) {
            bf16x8 v;
            #pragma unroll
            for (int j = 0; j < 8; ++j)
                v[j] = (short)f32_to_bf16(src[(size_t)(q * 8 + j) * (HIN * HIN)]);
            *(bf16x8*)(dst + q * 8) = v;
        }
    }
}

// Main GEMM: BK=64 fat iterations, full-tile gl_lds double buffer (128 KB LDS,
// 1 block/CU). Per iter: stage next 64KB tile, 2x{8 ds_read_b128 + 16 MFMA},
// vmcnt(0)+barrier (slack = one fat iteration). 512 thr = 8 waves (pxw,wm,wn).
__global__ __launch_bounds__(512, 2) void upconv8_kernel(
        const unsigned short* __restrict__ xq, const unsigned short* __restrict__ Aw3,
        const float* __restrict__ bv, float* __restrict__ out) {
    __shared__ __align__(16) unsigned short smem[65536];   // 128 KB
    const int d = blockIdx.x;
    const int dsw = (d & 7) * 64 + (d >> 3);     // bijective XCD chunk swizzle
    const int tile = dsw >> 1, py = dsw & 1;
    const int bi = tile >> 5;
    const int oy0 = (tile & 31) * 2;
    const int tid = threadIdx.x, lane = tid & 63, wv = tid >> 6;
    const int pxw = wv >> 2, wm = (wv >> 1) & 1, wn = wv & 1;
    const int rl = lane & 15, pl = lane >> 4;

    f32x4 acc[4][4];
    #pragma unroll
    for (int i = 0; i < 4; ++i)
        #pragma unroll
        for (int j = 0; j < 4; ++j)
            acc[i][j] = (f32x4){0.f, 0.f, 0.f, 0.f};

    // LDS layout (shorts): region(c, mat, px) = ((c*2 + mat)*2 + px) * 8192
    auto stage = [&](int c, int u) {
        const int tap = u >> 1, ty = tap >> 1, tx = tap & 1;
        const int gb0 = (u & 1) * 2;
        #pragma unroll
        for (int px = 0; px < 2; ++px) {
            const int par = py * 2 + px;
            #pragma unroll
            for (int h = 0; h < 2; ++h) {
                const int s = tid + h * 512;
                // A: contiguous pre-swizzled 16KB tile
                const unsigned short* ga = Aw3 + (((par * 8 + u) << 13) + s * 8);
                gl_lds16(ga, &smem[(((c * 2 + 0) * 2 + px) << 13) + s * 8]);
                // B: chunked xq, inverse-swizzled source
                const int row = s >> 3, partP = s & 7;
                const int partL = partP ^ (row & 7);
                const int g = gb0 + (partL >> 2), off = (partL & 3) * 8;
                const int rowg = oy0 + (row >> 6) + py + ty;
                const int col = (row & 63) + px + tx;
                const unsigned short* gb = xq +
                    ((((size_t)(bi * 4 + g) * HP + rowg) * HP + col) << 5) + off;
                gl_lds16(gb, &smem[(((c * 2 + 1) * 2 + px) << 13) + s * 8]);
            }
        }
    };

    stage(0, 0);
    vmw0();
    barx();

    #pragma unroll 2
    for (int u = 0; u < 8; ++u) {
        const int cur = u & 1;
        if (u < 7) stage(cur ^ 1, u + 1);
        const unsigned short* sa = &smem[((cur * 2 + 0) * 2 + pxw) << 13];
        const unsigned short* sb = &smem[((cur * 2 + 1) * 2 + pxw) << 13];
        #pragma unroll
        for (int kk = 0; kk < 2; ++kk) {
            bf16x8 af[4], bfr[4];
            #pragma unroll
            for (int f = 0; f < 4; ++f) {
                int ar = wm * 64 + f * 16 + rl;
                af[f] = *(const bf16x8*)&sa[ar * 64 + (((kk * 4 + pl) ^ (ar & 7)) * 8)];
                int bn = wn * 64 + f * 16 + rl;
                bfr[f] = *(const bf16x8*)&sb[bn * 64 + (((kk * 4 + pl) ^ (bn & 7)) * 8)];
            }
            #pragma unroll
            for (int fm = 0; fm < 4; ++fm)
                #pragma unroll
                for (int fn = 0; fn < 4; ++fn)
                    acc[fm][fn] = __builtin_amdgcn_mfma_f32_16x16x32_bf16(
                        af[fm], bfr[fn], acc[fm][fn], 0, 0, 0);
        }
        if (u < 7) { vmw0(); barx(); }
    }

    // coalesced epilogue via LDS: lf[co_l 0..31][r 0..1][xx 0..127], stride 264
    float* lf = (float*)smem;
    const int co_l = tid >> 4;
    const int rem = tid & 15, rr = rem >> 3, x16 = (rem & 7) * 16;
    const int co_g = (co_l >> 4) * 64 + (co_l & 15);
    const int yy = 2 * (oy0 + rr) + py;

    #pragma unroll
    for (int fm = 0; fm < 4; ++fm) {
        #pragma unroll
        for (int fn = 0; fn < 4; ++fn) {
            int n = wn * 64 + fn * 16 + rl;
            int r = n >> 6, xx = 2 * (n & 63) + pxw;
            #pragma unroll
            for (int j = 0; j < 4; ++j) {
                int col = wm * 16 + pl * 4 + j;
                lf[col * 264 + r * 132 + xx] = acc[fm][fn][j];
            }
        }
        lkw0();
        barx();
        const int co = co_g + fm * 16;
        const float bb = bv[co];
        float* op = out + (((size_t)bi * NCO + co) * 128 + yy) * 128 + x16;
        const float* sp = lf + co_l * 264 + rr * 132 + x16;
        #pragma unroll
        for (int q = 0; q < 4; ++q) {
            f32x4 v = *(const f32x4*)(sp + q * 4);
            v[0] += bb; v[1] += bb; v[2] += bb; v[3] += bb;
            *(f32x4*)(op + q * 4) = v;
        }
        if (fm < 3) barx();
    }
}

// -------- fallback (ws too small for xq): flat Weff + direct-x kernel --------
__global__ void weff_flat_kernel(const float* __restrict__ W,
                                 unsigned short* __restrict__ Aw) {
    int idx = blockIdx.x * 256 + threadIdx.x;   // Aw[par][co][512]
    int par = idx >> 16;
    int co  = (idx >> 9) & 127;
    int k   = idx & 511;
    int tap = k >> 7, ci = k & 127;
    Aw[idx] = f32_to_bf16(weff_sum(W + (co * NCI + ci) * 9,
                                   par >> 1, par & 1, tap >> 1, tap & 1));
}

__global__ __launch_bounds__(256) void upconv_fb_kernel(
        const float* __restrict__ x, const unsigned short* __restrict__ Aw,
        const float* __restrict__ bv, float* __restrict__ out) {
    __shared__ __align__(16) unsigned short A_lds[128 * 32];
    __shared__ __align__(16) unsigned short B_lds[128 * 32];
    const int par = blockIdx.y, py = par >> 1, px = par & 1;
    const int s0 = blockIdx.x * 128;
    const int bimg = s0 >> 12;
    const int oy0 = (s0 >> 6) & 63;
    const int tid = threadIdx.x;
    const int lane = tid & 63, wave = tid >> 6;
    const int wm = wave >> 1, wn = wave & 1;
    const float* xb = x + bimg * (NCI * HIN * HIN);
    f32x4 acc[4][4];
    #pragma unroll
    for (int i = 0; i < 4; ++i)
        #pragma unroll
        for (int j = 0; j < 4; ++j)
            acc[i][j] = (f32x4){0.f, 0.f, 0.f, 0.f};
    for (int kt = 0; kt < 16; ++kt) {
        const int tap = kt >> 2, ci0 = (kt & 3) * 32;
        const int ty = tap >> 1, tx = tap & 1;
        #pragma unroll
        for (int i = 0; i < 2; ++i) {
            int c = i * 256 + tid;
            *(bf16x8*)(&A_lds[c * 8]) = *(const bf16x8*)(Aw +
                ((par * 128 + (c >> 2)) * 512 + kt * 32 + (c & 3) * 8));
        }
        #pragma unroll
        for (int i = 0; i < 2; ++i) {
            int tsk = i * 256 + tid;
            int n = tsk & 127, kg = tsk >> 7;
            int r = n >> 6, ox = n & 63;
            int row = oy0 + r - 1 + py + ty;
            int col = ox - 1 + px + tx;
            bool ok = (row >= 0) & (row < HIN) & (col >= 0) & (col < HIN);
            const float* xp = xb + (((ci0 + kg * 8) * HIN + row) * HIN + col);
            bf16x8 v;
            #pragma unroll
            for (int q = 0; q < 8; ++q) {
                float f = ok ? xp[q * (HIN * HIN)] : 0.f;
                v[q] = (short)f32_to_bf16(f);
            }
            *(bf16x8*)(&B_lds[n * 32 + kg * 8]) = v;
        }
        __syncthreads();
        const int seg = (lane >> 4) * 8, rl2 = lane & 15;
        bf16x8 af[4], bfr[4];
        #pragma unroll
        for (int f = 0; f < 4; ++f)
            af[f] = *(const bf16x8*)(&A_lds[(wm * 64 + f * 16 + rl2) * 32 + seg]);
        #pragma unroll
        for (int f = 0; f < 4; ++f)
            bfr[f] = *(const bf16x8*)(&B_lds[(wn * 64 + f * 16 + rl2) * 32 + seg]);
        #pragma unroll
        for (int fm = 0; fm < 4; ++fm)
            #pragma unroll
            for (int fn = 0; fn < 4; ++fn)
                acc[fm][fn] = __builtin_amdgcn_mfma_f32_16x16x32_bf16(
                    af[fm], bfr[fn], acc[fm][fn], 0, 0, 0);
        __syncthreads();
    }
    #pragma unroll
    for (int fm = 0; fm < 4; ++fm) {
        const int co_b = wm * 64 + fm * 16 + (lane >> 4) * 4;
        float bias4[4];
        #pragma unroll
        for (int j = 0; j < 4; ++j) bias4[j] = bv[co_b + j];
        #pragma unroll
        for (int fn = 0; fn < 4; ++fn) {
            int n = wn * 64 + fn * 16 + (lane & 15);
            int s = s0 + n;
            int ox = s & 63, oy = (s >> 6) & 63, bi2 = s >> 12;
            int yy = 2 * oy + py, xx = 2 * ox + px;
            float* op = out + ((size_t)bi2 * 128 * 128 * 128) + (size_t)yy * 128 + xx;
            #pragma unroll
            for (int j = 0; j < 4; ++j)
                op[(size_t)(co_b + j) * (128 * 128)] = acc[fm][fn][j] + bias4[j];
        }
    }
}

extern "C" void kernel_launch(void* const* d_in, const int* in_sizes, int n_in,
                              void* d_out, int out_size, void* d_ws, size_t ws_size,
                              hipStream_t stream) {
    const float* x  = (const float*)d_in[0];
    const float* W  = (const float*)d_in[1];
    const float* bv = (const float*)d_in[2];
    float* out = (float*)d_out;
    unsigned short* Aw = (unsigned short*)d_ws;               // 512 KB
    const size_t aw_bytes = (size_t)4 * 8 * 8192 * sizeof(unsigned short);
    const size_t xq_bytes = (size_t)NB * 4 * HP * HP * 32 * sizeof(unsigned short);

    if (ws_size >= aw_bytes + xq_bytes) {
        unsigned short* xq = (unsigned short*)((char*)d_ws + aw_bytes);
        prep_kernel<<<1024 + NB * HP, 256, 0, stream>>>(W, x, Aw, xq);
        upconv8_kernel<<<512, 512, 0, stream>>>(xq, Aw, bv, out);
    } else {
        weff_flat_kernel<<<1024, 256, 0, stream>>>(W, Aw);
        upconv_fb_kernel<<<dim3(256, 4), 256, 0, stream>>>(x, Aw, bv, out);
    }
}

// Round 8
// 47.458 us; speedup vs baseline: 2.5091x; 1.1576x over previous
//
#include <hip/hip_runtime.h>
#include <stdint.h>

typedef short bf16x8 __attribute__((ext_vector_type(8)));
typedef float f32x4 __attribute__((ext_vector_type(4)));

#define NCI 128
#define NCO 128
#define HIN 64
#define HP  66
#define NB  8

__device__ __forceinline__ unsigned short f32_to_bf16(float f) {
    union { float f; uint32_t u; } v; v.f = f;
    return (unsigned short)((v.u + 0x7FFFu + ((v.u >> 16) & 1u)) >> 16);
}

__device__ __forceinline__ void gl_lds16(const void* g, void* l) {
    __builtin_amdgcn_global_load_lds(
        (const __attribute__((address_space(1))) unsigned int*)g,
        (__attribute__((address_space(3))) unsigned int*)l, 16, 0, 0);
}

__device__ __forceinline__ void vmw0() {
    asm volatile("s_waitcnt vmcnt(0)" ::: "memory");
}
__device__ __forceinline__ void lkw0() {
    asm volatile("s_waitcnt lgkmcnt(0)" ::: "memory");
}
__device__ __forceinline__ void barx() {
    asm volatile("" ::: "memory");
    __builtin_amdgcn_s_barrier();
    asm volatile("" ::: "memory");
}

// Effective 2x2-tap weight for parity (py,px), tap (ty,tx)
__device__ __forceinline__ float weff_sum(const float* wp, int py, int px, int ty, int tx) {
    float s = 0.f;
    #pragma unroll
    for (int ky = 0; ky < 3; ++ky) {
        bool iy = (py == 0) ? (ty == 0 ? (ky == 0) : (ky >= 1))
                            : (ty == 0 ? (ky <= 1) : (ky == 2));
        if (!iy) continue;
        #pragma unroll
        for (int kx = 0; kx < 3; ++kx) {
            bool ix = (px == 0) ? (tx == 0 ? (kx == 0) : (kx >= 1))
                                : (tx == 0 ? (kx <= 1) : (kx == 2));
            if (ix) s += wp[ky * 3 + kx];
        }
    }
    return s;
}

// ---- fused prologue ----
// blocks [0,1024): Weff -> Aw4, wave-fragment-major so a wave's A-frag load is
//   1 KB fully coalesced:  offset = (((par*16+kt)*4+wmq)*2 + f)*512 + pl*128 + rl*8 + e
//   content = Weff[par][co = wmq*32+f*16+rl][k = kt*32+pl*8+e]   (512 KB total)
// blocks [1024,1552): x [8][128][64][64] f32 -> xq [8][4][66][66][32] bf16
//   (ci-chunked NHWC, halo written here).
__global__ __launch_bounds__(256) void prep_kernel(
        const float* __restrict__ W, const float* __restrict__ x,
        unsigned short* __restrict__ Aw4, unsigned short* __restrict__ xq) {
    if (blockIdx.x < 1024) {
        int idx = blockIdx.x * 256 + threadIdx.x;     // 262144 total
        int e   = idx & 7;
        int rl  = (idx >> 3) & 15;
        int pl  = (idx >> 7) & 3;
        int f   = (idx >> 9) & 1;
        int wmq = (idx >> 10) & 3;
        int kt  = (idx >> 12) & 15;
        int par = idx >> 16;
        int co = wmq * 32 + f * 16 + rl;
        int k  = kt * 32 + pl * 8 + e;
        int tap = k >> 7, ci = k & 127;
        Aw4[idx] = f32_to_bf16(weff_sum(W + (co * NCI + ci) * 9,
                                        par >> 1, par & 1, tap >> 1, tap & 1));
    } else {
        const int bb = blockIdx.x - 1024;             // 528 blocks
        const int b = bb / HP, hp = bb % HP;
        const int t = threadIdx.x;
        if (hp == 0 || hp == HP - 1) {
            bf16x8 z = (bf16x8){0, 0, 0, 0, 0, 0, 0, 0};
            for (int i = t; i < 4 * HP * 4; i += 256) {
                int g = i / (HP * 4), rem = i % (HP * 4);
                unsigned short* dst = xq +
                    ((((size_t)(b * 4 + g) * HP + hp) * HP) << 5) + rem * 8;
                *(bf16x8*)dst = z;
            }
            return;
        }
        const int h = hp - 1;
        if (t < 32) {                                  // column halo wp = 0, 65
            bf16x8 z = (bf16x8){0, 0, 0, 0, 0, 0, 0, 0};
            int g = t >> 3, wpc = ((t >> 2) & 1) * (HP - 1), q = t & 3;
            unsigned short* dst = xq +
                ((((size_t)(b * 4 + g) * HP + hp) * HP + wpc) << 5) + q * 8;
            *(bf16x8*)dst = z;
        }
        const int w = t & 63, g = t >> 6;
        const float* src = x + ((size_t)(b * NCI + g * 32) * (HIN * HIN)) + h * HIN + w;
        unsigned short* dst = xq +
            ((((size_t)(b * 4 + g) * HP + hp) * HP + (w + 1)) << 5);
        #pragma unroll
        for (int q = 0; q < 4; ++q) {
            bf16x8 v;
            #pragma unroll
            for (int j = 0; j < 8; ++j)
                v[j] = (short)f32_to_bf16(src[(size_t)(q * 8 + j) * (HIN * HIN)]);
            *(bf16x8*)(dst + q * 8) = v;
        }
    }
}

// Main GEMM: barrier-free K-loop. B (3 rows x 66 cols x 128 ci = 50.7 KB) staged
// to LDS ONCE (covers all K=512); A streams global(L2)->reg, 1-ahead ping-pong.
// 512 thr = 8 waves: wmq(4 co-bands of 32) x pxw(2). Wave = 32co x 128sp.
// 2 blocks/CU (regs<=128, LDS 50.7KB) -> 16 free-running waves/CU.
__global__ __launch_bounds__(512, 4) void upconv9_kernel(
        const unsigned short* __restrict__ xq, const unsigned short* __restrict__ Aw4,
        const float* __restrict__ bv, float* __restrict__ out) {
    __shared__ __align__(16) unsigned short smem[25344];   // 50688 B
    const int d = blockIdx.x;
    const int dsw = (d & 7) * 64 + (d >> 3);     // bijective XCD chunk swizzle
    const int tile = dsw >> 1, py = dsw & 1;
    const int bi = tile >> 5;
    const int oy0 = (tile & 31) * 2;
    const int tid = threadIdx.x, lane = tid & 63, wv = tid >> 6;
    const int pxw = wv & 1, wmq = wv >> 1;
    const int rl = lane & 15, pl = lane >> 4;
    const int par = py * 2 + pxw;

    // ---- stage B once: slot dd -> (cell = dd>>4, chunk' = dd&15),
    //      chunk = chunk' ^ (col&15)  (bank swizzle; linear LDS dest, rule #21)
    #pragma unroll
    for (int i = 0; i < 7; ++i) {
        int dd = i * 512 + tid;
        if (dd < 3168) {
            int cell = dd >> 4, chq = dd & 15;
            int ry = cell / 66, colg = cell - ry * 66;
            int chunk = chq ^ (colg & 15);
            const unsigned short* gb = xq +
                ((((size_t)(bi * 4 + (chunk >> 2)) * HP + (oy0 + py + ry)) * HP + colg) << 5)
                + (chunk & 3) * 8;
            gl_lds16(gb, &smem[dd * 8]);
        }
    }

    f32x4 acc[2][8];
    #pragma unroll
    for (int i = 0; i < 2; ++i)
        #pragma unroll
        for (int j = 0; j < 8; ++j)
            acc[i][j] = (f32x4){0.f, 0.f, 0.f, 0.f};

    bf16x8 A0[2], A1[2];
    auto loadA = [&](bf16x8* Ad, int kt) {
        const unsigned short* p = Aw4 + ((((par * 16 + kt) * 4 + wmq)) << 10) + lane * 8;
        Ad[0] = *(const bf16x8*)p;
        Ad[1] = *(const bf16x8*)(p + 512);
    };

    loadA(A0, 0);
    vmw0();        // B staged + A0 ready
    barx();        // the ONLY pre-epilogue barrier

    #pragma unroll 2
    for (int kt = 0; kt < 16; ++kt) {
        if (kt < 15) loadA((kt & 1) ? A0 : A1, kt + 1);
        const bf16x8* Ac = (kt & 1) ? A1 : A0;
        const int ty = kt >> 3, tx = (kt >> 2) & 1, cq = kt & 3;
        #pragma unroll
        for (int half = 0; half < 2; ++half) {
            bf16x8 bfr[4];
            #pragma unroll
            for (int f = 0; f < 4; ++f) {
                int n = (half * 4 + f) * 16 + rl;
                int ry = (n >> 6) + ty;
                int colg = (n & 63) + pxw + tx;
                int chq = (cq * 4 + pl) ^ (colg & 15);
                bfr[f] = *(const bf16x8*)&smem[(((ry * 66 + colg) << 4) + chq) * 8];
            }
            #pragma unroll
            for (int fm = 0; fm < 2; ++fm)
                #pragma unroll
                for (int f = 0; f < 4; ++f)
                    acc[fm][half * 4 + f] = __builtin_amdgcn_mfma_f32_16x16x32_bf16(
                        Ac[fm], bfr[f], acc[fm][half * 4 + f], 0, 0, 0);
        }
    }

    barx();   // all waves done reading B before lf overwrite

    // coalesced epilogue via LDS: lf[co_l 0..31][r 0..1][xx 0..127], stride 264.
    // Round b: waves with wmq==b dump their full acc (co band b*32..b*32+31).
    float* lf = (float*)smem;
    const int co_l = tid >> 4;
    const int rr = (tid >> 3) & 1, x16 = (tid & 7) * 16;
    const int yy = 2 * (oy0 + rr) + py;

    #pragma unroll
    for (int b = 0; b < 4; ++b) {
        if (wmq == b) {
            #pragma unroll
            for (int fm = 0; fm < 2; ++fm)
                #pragma unroll
                for (int fn = 0; fn < 8; ++fn) {
                    int n = fn * 16 + rl;
                    int r = n >> 6, xx = 2 * (n & 63) + pxw;
                    #pragma unroll
                    for (int j = 0; j < 4; ++j)
                        lf[(fm * 16 + pl * 4 + j) * 264 + r * 132 + xx] = acc[fm][fn][j];
                }
        }
        lkw0();
        barx();
        const int co = b * 32 + co_l;
        const float bb = bv[co];
        float* op = out + (((size_t)bi * NCO + co) * 128 + yy) * 128 + x16;
        const float* sp = lf + co_l * 264 + rr * 132 + x16;
        #pragma unroll
        for (int q = 0; q < 4; ++q) {
            f32x4 v = *(const f32x4*)(sp + q * 4);
            v[0] += bb; v[1] += bb; v[2] += bb; v[3] += bb;
            *(f32x4*)(op + q * 4) = v;
        }
        if (b < 3) barx();
    }
}

// -------- fallback (ws too small for xq): flat Weff + direct-x kernel --------
__global__ void weff_flat_kernel(const float* __restrict__ W,
                                 unsigned short* __restrict__ Aw) {
    int idx = blockIdx.x * 256 + threadIdx.x;   // Aw[par][co][512]
    int par = idx >> 16;
    int co  = (idx >> 9) & 127;
    int k   = idx & 511;
    int tap = k >> 7, ci = k & 127;
    Aw[idx] = f32_to_bf16(weff_sum(W + (co * NCI + ci) * 9,
                                   par >> 1, par & 1, tap >> 1, tap & 1));
}

__global__ __launch_bounds__(256) void upconv_fb_kernel(
        const float* __restrict__ x, const unsigned short* __restrict__ Aw,
        const float* __restrict__ bv, float* __restrict__ out) {
    __shared__ __align__(16) unsigned short A_lds[128 * 32];
    __shared__ __align__(16) unsigned short B_lds[128 * 32];
    const int par = blockIdx.y, py = par >> 1, px = par & 1;
    const int s0 = blockIdx.x * 128;
    const int bimg = s0 >> 12;
    const int oy0 = (s0 >> 6) & 63;
    const int tid = threadIdx.x;
    const int lane = tid & 63, wave = tid >> 6;
    const int wm = wave >> 1, wn = wave & 1;
    const float* xb = x + bimg * (NCI * HIN * HIN);
    f32x4 acc[4][4];
    #pragma unroll
    for (int i = 0; i < 4; ++i)
        #pragma unroll
        for (int j = 0; j < 4; ++j)
            acc[i][j] = (f32x4){0.f, 0.f, 0.f, 0.f};
    for (int kt = 0; kt < 16; ++kt) {
        const int tap = kt >> 2, ci0 = (kt & 3) * 32;
        const int ty = tap >> 1, tx = tap & 1;
        #pragma unroll
        for (int i = 0; i < 2; ++i) {
            int c = i * 256 + tid;
            *(bf16x8*)(&A_lds[c * 8]) = *(const bf16x8*)(Aw +
                ((par * 128 + (c >> 2)) * 512 + kt * 32 + (c & 3) * 8));
        }
        #pragma unroll
        for (int i = 0; i < 2; ++i) {
            int tsk = i * 256 + tid;
            int n = tsk & 127, kg = tsk >> 7;
            int r = n >> 6, ox = n & 63;
            int row = oy0 + r - 1 + py + ty;
            int col = ox - 1 + px + tx;
            bool ok = (row >= 0) & (row < HIN) & (col >= 0) & (col < HIN);
            const float* xp = xb + (((ci0 + kg * 8) * HIN + row) * HIN + col);
            bf16x8 v;
            #pragma unroll
            for (int q = 0; q < 8; ++q) {
                float f = ok ? xp[q * (HIN * HIN)] : 0.f;
                v[q] = (short)f32_to_bf16(f);
            }
            *(bf16x8*)(&B_lds[n * 32 + kg * 8]) = v;
        }
        __syncthreads();
        const int seg = (lane >> 4) * 8, rl2 = lane & 15;
        bf16x8 af[4], bfr[4];
        #pragma unroll
        for (int f = 0; f < 4; ++f)
            af[f] = *(const bf16x8*)(&A_lds[(wm * 64 + f * 16 + rl2) * 32 + seg]);
        #pragma unroll
        for (int f = 0; f < 4; ++f)
            bfr[f] = *(const bf16x8*)(&B_lds[(wn * 64 + f * 16 + rl2) * 32 + seg]);
        #pragma unroll
        for (int fm = 0; fm < 4; ++fm)
            #pragma unroll
            for (int fn = 0; fn < 4; ++fn)
                acc[fm][fn] = __builtin_amdgcn_mfma_f32_16x16x32_bf16(
                    af[fm], bfr[fn], acc[fm][fn], 0, 0, 0);
        __syncthreads();
    }
    #pragma unroll
    for (int fm = 0; fm < 4; ++fm) {
        const int co_b = wm * 64 + fm * 16 + (lane >> 4) * 4;
        float bias4[4];
        #pragma unroll
        for (int j = 0; j < 4; ++j) bias4[j] = bv[co_b + j];
        #pragma unroll
        for (int fn = 0; fn < 4; ++fn) {
            int n = wn * 64 + fn * 16 + (lane & 15);
            int s = s0 + n;
            int ox = s & 63, oy = (s >> 6) & 63, bi2 = s >> 12;
            int yy = 2 * oy + py, xx = 2 * ox + px;
            float* op = out + ((size_t)bi2 * 128 * 128 * 128) + (size_t)yy * 128 + xx;
            #pragma unroll
            for (int j = 0; j < 4; ++j)
                op[(size_t)(co_b + j) * (128 * 128)] = acc[fm][fn][j] + bias4[j];
        }
    }
}

extern "C" void kernel_launch(void* const* d_in, const int* in_sizes, int n_in,
                              void* d_out, int out_size, void* d_ws, size_t ws_size,
                              hipStream_t stream) {
    const float* x  = (const float*)d_in[0];
    const float* W  = (const float*)d_in[1];
    const float* bv = (const float*)d_in[2];
    float* out = (float*)d_out;
    unsigned short* Aw = (unsigned short*)d_ws;               // 512 KB
    const size_t aw_bytes = (size_t)4 * 16 * 4 * 2 * 512 * sizeof(unsigned short);
    const size_t xq_bytes = (size_t)NB * 4 * HP * HP * 32 * sizeof(unsigned short);

    if (ws_size >= aw_bytes + xq_bytes) {
        unsigned short* xq = (unsigned short*)((char*)d_ws + aw_bytes);
        prep_kernel<<<1024 + NB * HP, 256, 0, stream>>>(W, x, Aw, xq);
        upconv9_kernel<<<512, 512, 0, stream>>>(xq, Aw, bv, out);
    } else {
        weff_flat_kernel<<<1024, 256, 0, stream>>>(W, Aw);
        upconv_fb_kernel<<<dim3(256, 4), 256, 0, stream>>>(x, Aw, bv, out);
    }
}